// Round 4
// baseline (523.468 us; speedup 1.0000x reference)
//
#include <hip/hip_runtime.h>

// Problem constants
#define BB 8192
#define HH 1024
#define KK 512

typedef __bf16 bf16x8 __attribute__((ext_vector_type(8)));
typedef __bf16 bf16x4 __attribute__((ext_vector_type(4)));
typedef float  f32x4  __attribute__((ext_vector_type(4)));

#define GLOAD_LDS16(gptr, lptr)                                                   \
  __builtin_amdgcn_global_load_lds((const __attribute__((address_space(1))) void*)(gptr), \
                                   (__attribute__((address_space(3))) void*)(lptr), 16, 0, 0)

static __device__ __forceinline__ void split_bf16(float f, __bf16& hi, __bf16& lo) {
  hi = (__bf16)f;
  lo = (__bf16)(f - (float)hi);
}

// ---------------- P1: split x into hi/lo bf16 ----------------
__global__ __launch_bounds__(256) void p1_split(const float* __restrict__ x,
                                                __bf16* __restrict__ xh,
                                                __bf16* __restrict__ xl) {
  const size_t i = ((size_t)blockIdx.x * 256 + threadIdx.x) * 4;
  const float4 v = *(const float4*)(x + i);
  float f[4] = {v.x, v.y, v.z, v.w};
  bf16x4 hv, lv;
#pragma unroll
  for (int j = 0; j < 4; ++j) {
    __bf16 h, l; split_bf16(f[j], h, l);
    hv[j] = h; lv[j] = l;
  }
  *(bf16x4*)(xh + i) = hv;
  *(bf16x4*)(xl + i) = lv;
}

// ---------------- P2: build W1' [2048, 3072] = [Whi | Wlo | Whi] of [W_mu; W_ls]
__global__ __launch_bounds__(256) void p2_w1(const float* __restrict__ Wmu,
                                             const float* __restrict__ Wls,
                                             __bf16* __restrict__ W1p) {
  const int j = blockIdx.y;                       // 0..2047 output column
  const int k = blockIdx.x * 256 + threadIdx.x;   // 0..3071 reduction index
  const int c = k >> 10, h = k & 1023;
  const float* src = (j < 1024) ? Wmu : Wls;
  const float f = src[(size_t)(j & 1023) * 1024 + h];
  __bf16 hi, lo; split_bf16(f, hi, lo);
  W1p[(size_t)j * 3072 + k] = (c == 1) ? lo : hi;
}

// ---------------- P3: cluster stats + W2' [512, 6144] = [Whi | Wlo | Whi] of [inv | -2*mu_inv]
// Also zeroes the att accumulator (runs before k4 in stream order).
__global__ __launch_bounds__(256) void p3_cluster(const float* __restrict__ muc,
                                                  const float* __restrict__ lsc,
                                                  __bf16* __restrict__ W2p,
                                                  float* __restrict__ c2,
                                                  float* __restrict__ logdet,
                                                  float* __restrict__ acc) {
  const int k = blockIdx.x;
  const int t = threadIdx.x;
  if (t == 0) acc[k] = 0.f;
  float c2acc = 0.f, ldacc = 0.f;
  const size_t rb = (size_t)k * 6144;
#pragma unroll
  for (int i = 0; i < 4; ++i) {
    const int h = t + i * 256;
    const float l = lsc[(size_t)k * 1024 + h];
    const float m = muc[(size_t)k * 1024 + h];
    const float inv = expf(-l);
    const float mi = m * inv;
    c2acc += m * mi;
    ldacc += l;
    __bf16 h0, l0, h1, l1;
    split_bf16(inv, h0, l0);
    split_bf16(-2.f * mi, h1, l1);
    W2p[rb + h]        = h0; W2p[rb + 1024 + h] = h1;   // chunk0: hi
    W2p[rb + 2048 + h] = l0; W2p[rb + 3072 + h] = l1;   // chunk1: lo
    W2p[rb + 4096 + h] = h0; W2p[rb + 5120 + h] = h1;   // chunk2: hi
  }
#pragma unroll
  for (int off = 32; off; off >>= 1) {
    c2acc += __shfl_down(c2acc, off);
    ldacc += __shfl_down(ldacc, off);
  }
  __shared__ float r4[8];
  if ((t & 63) == 0) { r4[(t >> 6)] = c2acc; r4[4 + (t >> 6)] = ldacc; }
  __syncthreads();
  if (t == 0) {
    c2[k]     = r4[0] + r4[1] + r4[2] + r4[3];
    logdet[k] = r4[4] + r4[5] + r4[6] + r4[7];
  }
}

// ---------------- GEMM1: C1[8192,2048] = [xh|xh|xl] (K=3072) * W1p[2048,3072]^T
// 128x128 tile, BK=64, 4 waves, 4x4 frags of 16x16x32 bf16; gload_lds + XOR swizzle
__global__ __launch_bounds__(256, 2) void gemm1(const __bf16* __restrict__ Ah,
                                                const __bf16* __restrict__ Al,
                                                const __bf16* __restrict__ W,
                                                float* __restrict__ C) {
  __shared__ __align__(16) __bf16 ldsA[128 * 64];
  __shared__ __align__(16) __bf16 ldsB[128 * 64];

  const int t = threadIdx.x;
  const int wv = t >> 6, lane = t & 63;
  const int l15 = lane & 15, l4 = lane >> 4;
  const int wr = wv >> 1, wc = wv & 1;
  const int bm0 = blockIdx.x * 128;
  const int bn0 = blockIdx.y * 128;

  f32x4 acc[4][4] = {};

  for (int k0 = 0; k0 < 3072; k0 += 64) {
    const int chunk = k0 >> 10;
    const int kin = k0 & 1023;
    const __bf16* Abase = (chunk == 2) ? Al : Ah;

#pragma unroll
    for (int i = 0; i < 4; ++i) {
      const int obase = i * 4096 + wv * 1024;   // wave-uniform LDS byte base
      const int o = obase + lane * 16;
      const int row = o >> 7;
      const int cb = o & 127;
      const int cbs = cb ^ ((row & 7) << 4);    // inverse-swizzled source column byte
      GLOAD_LDS16(Abase + (size_t)(bm0 + row) * 1024 + kin + (cbs >> 1), (char*)ldsA + obase);
    }
#pragma unroll
    for (int i = 0; i < 4; ++i) {
      const int obase = i * 4096 + wv * 1024;
      const int o = obase + lane * 16;
      const int row = o >> 7;
      const int cb = o & 127;
      const int cbs = cb ^ ((row & 7) << 4);
      GLOAD_LDS16(W + (size_t)(bn0 + row) * 3072 + k0 + (cbs >> 1), (char*)ldsB + obase);
    }
    __syncthreads();

#pragma unroll
    for (int kkk = 0; kkk < 2; ++kkk) {
      bf16x8 av[4], bv[4];
#pragma unroll
      for (int m = 0; m < 4; ++m) {
        const int row = wr * 64 + m * 16 + l15;
        const int cb = kkk * 64 + l4 * 16;
        av[m] = *(const bf16x8*)((const char*)ldsA + row * 128 + (cb ^ ((row & 7) << 4)));
      }
#pragma unroll
      for (int n = 0; n < 4; ++n) {
        const int row = wc * 64 + n * 16 + l15;
        const int cb = kkk * 64 + l4 * 16;
        bv[n] = *(const bf16x8*)((const char*)ldsB + row * 128 + (cb ^ ((row & 7) << 4)));
      }
#pragma unroll
      for (int m = 0; m < 4; ++m)
#pragma unroll
        for (int n = 0; n < 4; ++n)
          acc[m][n] = __builtin_amdgcn_mfma_f32_16x16x32_bf16(av[m], bv[n], acc[m][n], 0, 0, 0);
    }
    __syncthreads();
  }

#pragma unroll
  for (int m = 0; m < 4; ++m) {
#pragma unroll
    for (int n = 0; n < 4; ++n) {
      const int gr0 = bm0 + wr * 64 + m * 16 + l4 * 4;
      const int gc  = bn0 + wc * 64 + n * 16 + l15;
#pragma unroll
      for (int j = 0; j < 4; ++j)
        C[(size_t)(gr0 + j) * 2048 + gc] = acc[m][n][j];
    }
  }
}

// ---------------- K2: z -> out; C1 rewritten in place to [mu_biased | mu^2+exp(ls)]; lss
__global__ __launch_bounds__(256) void k2_build(float* __restrict__ C1,
                                                const float* __restrict__ bmu,
                                                const float* __restrict__ bls,
                                                const float* __restrict__ eps,
                                                float* __restrict__ z_out,
                                                float* __restrict__ ls_sum) {
  const int b = blockIdx.x;
  const int t = threadIdx.x;
  float lsacc = 0.f;
  const size_t base2 = (size_t)b * 2048;
  const size_t base1 = (size_t)b * 1024;
#pragma unroll
  for (int i = 0; i < 4; ++i) {
    const int h = t + i * 256;
    const float mu = C1[base2 + h] + bmu[h];
    const float ls = C1[base2 + 1024 + h] + bls[h];
    const float e = eps[base1 + h];
    const float sh = expf(0.5f * ls);           // exp(ls/2)
    const float z = fmaf(sh, e, mu);
    z_out[base1 + h] = z;
    lsacc += ls;
    C1[base2 + h] = mu;                         // biased mu
    C1[base2 + 1024 + h] = fmaf(mu, mu, sh * sh);  // q = mu^2 + exp(ls)
  }
#pragma unroll
  for (int off = 32; off; off >>= 1) lsacc += __shfl_down(lsacc, off);
  __shared__ float r4[4];
  if ((t & 63) == 0) r4[t >> 6] = lsacc;
  __syncthreads();
  if (t == 0) ls_sum[b] = r4[0] + r4[1] + r4[2] + r4[3];
}

// ---------------- GEMM2: C2[8192,512] partial sums, split-K + 2 variants
// blockIdx.z: bit0 = variant (0: mahal(z)-c2, 1: E@inv + mahal(mu)-c2), bit1 = K-half
// zv=0: A=[z^2 | z] ; zv=1: A=[q | mu], q=mu^2+exp(ls); chunks 0,1 -> hi(A), 2 -> lo(A)
__global__ __launch_bounds__(256, 2) void gemm2_fly(const float* __restrict__ C1,
                                                    const float* __restrict__ zbuf,
                                                    const __bf16* __restrict__ W2,
                                                    float* __restrict__ Cpart) {
  const int zv = blockIdx.z & 1;
  const int ks = blockIdx.z >> 1;
  // slice order: [m_s0][m_s1][a_s0][a_s1]
  float* Cc = Cpart + ((size_t)(zv * 2 + ks)) * BB * KK;

  __shared__ __align__(16) __bf16 ldsA[128 * 64];
  __shared__ __align__(16) __bf16 ldsB[128 * 64];

  const int t = threadIdx.x;
  const int wv = t >> 6, lane = t & 63;
  const int l15 = lane & 15, l4 = lane >> 4;
  const int wr = wv >> 1, wc = wv & 1;
  const int bm0 = blockIdx.x * 128;
  const int bn0 = blockIdx.y * 128;

  f32x4 acc[4][4] = {};

  const int kbeg = ks * 3072;
  for (int k0 = kbeg; k0 < kbeg + 3072; k0 += 64) {
    const int chunk = k0 >> 11;
    const int kin = k0 & 2047;
    const bool quad = kin < 1024;
    const int hcol = quad ? kin : (kin - 1024);

    // stage B via global_load_lds (linear LDS dest, pre-swizzled source)
#pragma unroll
    for (int i = 0; i < 4; ++i) {
      const int obase = i * 4096 + wv * 1024;
      const int o = obase + lane * 16;
      const int row = o >> 7;
      const int cb = o & 127;
      const int cbs = cb ^ ((row & 7) << 4);
      GLOAD_LDS16(W2 + (size_t)(bn0 + row) * 6144 + k0 + (cbs >> 1), (char*)ldsB + obase);
    }

    // stage A on the fly: f32 loads -> chunk value -> swizzled ds_write_b128
#pragma unroll
    for (int v = 0; v < 4; ++v) {
      const int id = v * 256 + t;          // 0..1023 -> (row, col8)
      const int row = id >> 3;
      const int c8 = id & 7;
      const size_t gr = (size_t)(bm0 + row);
      const int jc = hcol + c8 * 8;
      const float* src = (zv == 0) ? (zbuf + gr * 1024 + jc)
                                   : (C1 + gr * 2048 + (quad ? 1024 : 0) + jc);
      const float4 a = *(const float4*)(src);
      const float4 b = *(const float4*)(src + 4);
      float vals[8] = {a.x, a.y, a.z, a.w, b.x, b.y, b.z, b.w};
      if (zv == 0 && quad) {
#pragma unroll
        for (int j = 0; j < 8; ++j) vals[j] = vals[j] * vals[j];
      }
      bf16x8 w;
      if (chunk < 2) {
#pragma unroll
        for (int j = 0; j < 8; ++j) w[j] = (__bf16)vals[j];
      } else {
#pragma unroll
        for (int j = 0; j < 8; ++j) {
          const __bf16 h = (__bf16)vals[j];
          w[j] = (__bf16)(vals[j] - (float)h);
        }
      }
      const int cb = c8 * 16;
      *(bf16x8*)((char*)ldsA + row * 128 + (cb ^ ((row & 7) << 4))) = w;
    }
    __syncthreads();

#pragma unroll
    for (int kkk = 0; kkk < 2; ++kkk) {
      bf16x8 av[4], bv[4];
#pragma unroll
      for (int m = 0; m < 4; ++m) {
        const int row = wr * 64 + m * 16 + l15;
        const int cb = kkk * 64 + l4 * 16;
        av[m] = *(const bf16x8*)((const char*)ldsA + row * 128 + (cb ^ ((row & 7) << 4)));
      }
#pragma unroll
      for (int n = 0; n < 4; ++n) {
        const int row = wc * 64 + n * 16 + l15;
        const int cb = kkk * 64 + l4 * 16;
        bv[n] = *(const bf16x8*)((const char*)ldsB + row * 128 + (cb ^ ((row & 7) << 4)));
      }
#pragma unroll
      for (int m = 0; m < 4; ++m)
#pragma unroll
        for (int n = 0; n < 4; ++n)
          acc[m][n] = __builtin_amdgcn_mfma_f32_16x16x32_bf16(av[m], bv[n], acc[m][n], 0, 0, 0);
    }
    __syncthreads();
  }

#pragma unroll
  for (int m = 0; m < 4; ++m) {
#pragma unroll
    for (int n = 0; n < 4; ++n) {
      const int gr0 = bm0 + wr * 64 + m * 16 + l4 * 4;
      const int gc  = bn0 + wc * 64 + n * 16 + l15;
#pragma unroll
      for (int j = 0; j < 4; ++j)
        Cc[(size_t)(gr0 + j) * 512 + gc] = acc[m][n][j];
    }
  }
}

// ---------------- K4: per-row softmax/loss + att column accumulation
__global__ __launch_bounds__(256) void k4_rows(const float* __restrict__ Cpart,
                                               const float* __restrict__ c2,
                                               const float* __restrict__ logdet,
                                               const float* __restrict__ ls_sum,
                                               float* __restrict__ out_loss,
                                               float* __restrict__ acc) {
  const float* C2m0 = Cpart;
  const float* C2m1 = Cpart + (size_t)BB * KK;
  const float* C2a0 = Cpart + (size_t)2 * BB * KK;
  const float* C2a1 = Cpart + (size_t)3 * BB * KK;
  const int t = threadIdx.x;
  const int wv = t >> 6, lane = t & 63;
  __shared__ float sacc[512];
  sacc[t] = 0.f; sacc[t + 256] = 0.f;
  __syncthreads();
  float c2r[8], avr[8], attsum[8];
#pragma unroll
  for (int i = 0; i < 8; ++i) {
    const int k = lane + i * 64;
    c2r[i] = c2[k];
    avr[i] = logdet[k] + c2r[i];
    attsum[i] = 0.f;
  }
  for (int r = 0; r < 8; ++r) {
    const int b = blockIdx.x * 32 + wv * 8 + r;
    const size_t rb = (size_t)b * 512;
    float mv[8], ev[8];
    float lm = 3.4e38f;
#pragma unroll
    for (int i = 0; i < 8; ++i) {
      const size_t idx = rb + lane + i * 64;
      mv[i] = C2m0[idx] + C2m1[idx] + c2r[i];   // mahal(z)
      lm = fminf(lm, mv[i]);
    }
#pragma unroll
    for (int off = 32; off; off >>= 1) lm = fminf(lm, __shfl_xor(lm, off));
    float s = 0.f, dot = 0.f;
#pragma unroll
    for (int i = 0; i < 8; ++i) {
      const size_t idx = rb + lane + i * 64;
      const float e = expf(lm - mv[i]);
      const float avg = (avr[i] + C2a0[idx] + C2a1[idx]) * (1.f / 1024.f);
      ev[i] = e;
      s += e;
      dot = fmaf(e, avg, dot);
    }
#pragma unroll
    for (int off = 32; off; off >>= 1) {
      s   += __shfl_xor(s, off);
      dot += __shfl_xor(dot, off);
    }
    const float inv_s = 1.f / s;
    if (lane == 0)
      out_loss[b] = 0.5f * (dot * inv_s) - 0.5f * (1.f + ls_sum[b] * (1.f / 1024.f));
#pragma unroll
    for (int i = 0; i < 8; ++i) attsum[i] += ev[i] * inv_s;
  }
#pragma unroll
  for (int i = 0; i < 8; ++i) atomicAdd(&sacc[lane + i * 64], attsum[i]);
  __syncthreads();
  atomicAdd(&acc[t], sacc[t]);
  atomicAdd(&acc[t + 256], sacc[t + 256]);
}

// ---------------- K6: categorical loss scalar
__global__ __launch_bounds__(512) void k6_final(const float* __restrict__ acc,
                                                float* __restrict__ out) {
  const int t = threadIdx.x;
  const float cm = acc[t] * (1.f / 8192.f);
  float v = cm * logf(cm);
#pragma unroll
  for (int off = 32; off; off >>= 1) v += __shfl_xor(v, off);
  __shared__ float r8[8];
  if ((t & 63) == 0) r8[t >> 6] = v;
  __syncthreads();
  if (t == 0) {
    float s = 0.f;
#pragma unroll
    for (int i = 0; i < 8; ++i) s += r8[i];
    out[0] = s * (1.f / 512.f);
  }
}

extern "C" void kernel_launch(void* const* d_in, const int* in_sizes, int n_in,
                              void* d_out, int out_size, void* d_ws, size_t ws_size,
                              hipStream_t stream) {
  const float* x   = (const float*)d_in[0];
  const float* Wmu = (const float*)d_in[1];
  const float* bmu = (const float*)d_in[2];
  const float* Wls = (const float*)d_in[3];
  const float* bls = (const float*)d_in[4];
  const float* muc = (const float*)d_in[5];
  const float* lsc = (const float*)d_in[6];
  const float* eps = (const float*)d_in[7];
  float* out = (float*)d_out;

  char* p = (char*)d_ws;
  auto carve = [&](size_t bytes) {
    char* r = p;
    p += (bytes + 255) & ~(size_t)255;
    return r;
  };
  // persistent
  float*  C1  = (float*) carve((size_t)BB * 2048 * 4);          // 67.1 MB
  __bf16* W2p = (__bf16*)carve((size_t)KK * 6144 * 2);          //  6.3 MB
  float*  c2v = (float*) carve(KK * 4);
  float*  ldv = (float*) carve(KK * 4);
  float*  lss = (float*) carve(BB * 4);
  float*  acc = (float*) carve(KK * 4);
  // union region: {xh, xl, W1p} (phase 1) overlaid by Cpart[4 slices] (phase 3+)
  char* uni = carve((size_t)4 * BB * KK * 4);                   // 67.1 MB
  __bf16* xh  = (__bf16*)uni;
  __bf16* xl  = (__bf16*)(uni + (size_t)BB * HH * 2);
  __bf16* W1p = (__bf16*)(uni + (size_t)BB * HH * 4);
  float*  Cpart = (float*)uni;

  float* z_out    = out;
  float* loss_out = out + (size_t)BB * HH;
  float* cate_out = loss_out + BB;

  p1_split<<<dim3(BB * HH / 1024), 256, 0, stream>>>(x, xh, xl);
  p2_w1<<<dim3(12, 2048), 256, 0, stream>>>(Wmu, Wls, W1p);
  p3_cluster<<<dim3(KK), 256, 0, stream>>>(muc, lsc, W2p, c2v, ldv, acc);

  // GEMM1: [8192 x 3072] * [2048 x 3072]^T -> C1 (mu_z | ls_z, pre-bias)
  gemm1<<<dim3(BB / 128, 2048 / 128), 256, 0, stream>>>(xh, xl, W1p, C1);

  k2_build<<<dim3(BB), 256, 0, stream>>>(C1, bmu, bls, eps, z_out, lss);

  // GEMM2: split-K x 2 variants -> 4 partial slices
  gemm2_fly<<<dim3(BB / 128, KK / 128, 4), 256, 0, stream>>>(C1, z_out, W2p, Cpart);

  k4_rows<<<dim3(BB / 32), 256, 0, stream>>>(Cpart, c2v, ldv, lss, loss_out, acc);
  k6_final<<<dim3(1), 512, 0, stream>>>(acc, cate_out);
}

// Round 6
// 453.691 us; speedup vs baseline: 1.1538x; 1.1538x over previous
//
#include <hip/hip_runtime.h>

// Problem constants
#define BB 8192
#define HH 1024
#define KK 512

typedef __bf16 bf16x8 __attribute__((ext_vector_type(8)));
typedef __bf16 bf16x4 __attribute__((ext_vector_type(4)));
typedef float  f32x4  __attribute__((ext_vector_type(4)));

#define GLOAD_LDS16(gptr, lptr)                                                   \
  __builtin_amdgcn_global_load_lds((const __attribute__((address_space(1))) void*)(gptr), \
                                   (__attribute__((address_space(3))) void*)(lptr), 16, 0, 0)

static __device__ __forceinline__ void split_bf16(float f, __bf16& hi, __bf16& lo) {
  hi = (__bf16)f;
  lo = (__bf16)(f - (float)hi);
}

// ---------------- P1: split x into hi/lo bf16 ----------------
__global__ __launch_bounds__(256) void p1_split(const float* __restrict__ x,
                                                __bf16* __restrict__ xh,
                                                __bf16* __restrict__ xl) {
  const size_t i = ((size_t)blockIdx.x * 256 + threadIdx.x) * 4;
  const float4 v = *(const float4*)(x + i);
  float f[4] = {v.x, v.y, v.z, v.w};
  bf16x4 hv, lv;
#pragma unroll
  for (int j = 0; j < 4; ++j) {
    __bf16 h, l; split_bf16(f[j], h, l);
    hv[j] = h; lv[j] = l;
  }
  *(bf16x4*)(xh + i) = hv;
  *(bf16x4*)(xl + i) = lv;
}

// ---------------- P2: build W1' [2048, 3072] = [Whi | Wlo | Whi] of [W_mu; W_ls]
__global__ __launch_bounds__(256) void p2_w1(const float* __restrict__ Wmu,
                                             const float* __restrict__ Wls,
                                             __bf16* __restrict__ W1p) {
  const int j = blockIdx.y;                       // 0..2047 output column
  const int k = blockIdx.x * 256 + threadIdx.x;   // 0..3071 reduction index
  const int c = k >> 10, h = k & 1023;
  const float* src = (j < 1024) ? Wmu : Wls;
  const float f = src[(size_t)(j & 1023) * 1024 + h];
  __bf16 hi, lo; split_bf16(f, hi, lo);
  W1p[(size_t)j * 3072 + k] = (c == 1) ? lo : hi;
}

// ---------------- P3: cluster stats + W2' [512, 6144] = [Whi | Wlo | Whi] of [inv | -2*mu_inv]
__global__ __launch_bounds__(256) void p3_cluster(const float* __restrict__ muc,
                                                  const float* __restrict__ lsc,
                                                  __bf16* __restrict__ W2p,
                                                  float* __restrict__ c2,
                                                  float* __restrict__ logdet,
                                                  float* __restrict__ acc) {
  const int k = blockIdx.x;
  const int t = threadIdx.x;
  if (t == 0) acc[k] = 0.f;
  float c2acc = 0.f, ldacc = 0.f;
  const size_t rb = (size_t)k * 6144;
#pragma unroll
  for (int i = 0; i < 4; ++i) {
    const int h = t + i * 256;
    const float l = lsc[(size_t)k * 1024 + h];
    const float m = muc[(size_t)k * 1024 + h];
    const float inv = expf(-l);
    const float mi = m * inv;
    c2acc += m * mi;
    ldacc += l;
    __bf16 h0, l0, h1, l1;
    split_bf16(inv, h0, l0);
    split_bf16(-2.f * mi, h1, l1);
    W2p[rb + h]        = h0; W2p[rb + 1024 + h] = h1;   // chunk0: hi
    W2p[rb + 2048 + h] = l0; W2p[rb + 3072 + h] = l1;   // chunk1: lo
    W2p[rb + 4096 + h] = h0; W2p[rb + 5120 + h] = h1;   // chunk2: hi
  }
#pragma unroll
  for (int off = 32; off; off >>= 1) {
    c2acc += __shfl_down(c2acc, off);
    ldacc += __shfl_down(ldacc, off);
  }
  __shared__ float r4[8];
  if ((t & 63) == 0) { r4[(t >> 6)] = c2acc; r4[4 + (t >> 6)] = ldacc; }
  __syncthreads();
  if (t == 0) {
    c2[k]     = r4[0] + r4[1] + r4[2] + r4[3];
    logdet[k] = r4[4] + r4[5] + r4[6] + r4[7];
  }
}

// ---------------- GEMM1: C1[8192,2048] = [xh|xh|xl] (K=3072) * W1p[2048,3072]^T
// 128x128 tile, BK=64, 4 waves; 2-phase double-buffered: prefetch t+1 before compute t.
__global__ __launch_bounds__(256, 2) void gemm1(const __bf16* __restrict__ Ah,
                                                const __bf16* __restrict__ Al,
                                                const __bf16* __restrict__ W,
                                                float* __restrict__ C) {
  __shared__ __align__(16) __bf16 ldsA[2][128 * 64];
  __shared__ __align__(16) __bf16 ldsB[2][128 * 64];

  const int t = threadIdx.x;
  const int wv = t >> 6, lane = t & 63;
  const int l15 = lane & 15, l4 = lane >> 4;
  const int wr = wv >> 1, wc = wv & 1;
  const int bm0 = blockIdx.x * 128;
  const int bn0 = blockIdx.y * 128;

  f32x4 acc[4][4] = {};

  auto stage = [&](int k0, int b) {
    const int chunk = k0 >> 10;
    const int kin = k0 & 1023;
    const __bf16* Abase = (chunk == 2) ? Al : Ah;
#pragma unroll
    for (int i = 0; i < 4; ++i) {
      const int obase = i * 4096 + wv * 1024;   // wave-uniform LDS byte base
      const int o = obase + lane * 16;
      const int row = o >> 7;
      const int cb = o & 127;
      const int cbs = cb ^ ((row & 7) << 4);    // inverse-swizzled source column byte
      GLOAD_LDS16(Abase + (size_t)(bm0 + row) * 1024 + kin + (cbs >> 1), (char*)ldsA[b] + obase);
      GLOAD_LDS16(W + (size_t)(bn0 + row) * 3072 + k0 + (cbs >> 1), (char*)ldsB[b] + obase);
    }
  };

  stage(0, 0);
  __syncthreads();
  int cur = 0;

  for (int tt = 0; tt < 48; ++tt) {
    if (tt < 47) stage((tt + 1) * 64, cur ^ 1);   // prefetch next tile (in flight during MFMA)

#pragma unroll
    for (int kkk = 0; kkk < 2; ++kkk) {
      bf16x8 av[4], bv[4];
#pragma unroll
      for (int m = 0; m < 4; ++m) {
        const int row = wr * 64 + m * 16 + l15;
        const int cb = kkk * 64 + l4 * 16;
        av[m] = *(const bf16x8*)((const char*)ldsA[cur] + row * 128 + (cb ^ ((row & 7) << 4)));
      }
#pragma unroll
      for (int n = 0; n < 4; ++n) {
        const int row = wc * 64 + n * 16 + l15;
        const int cb = kkk * 64 + l4 * 16;
        bv[n] = *(const bf16x8*)((const char*)ldsB[cur] + row * 128 + (cb ^ ((row & 7) << 4)));
      }
#pragma unroll
      for (int m = 0; m < 4; ++m)
#pragma unroll
        for (int n = 0; n < 4; ++n)
          acc[m][n] = __builtin_amdgcn_mfma_f32_16x16x32_bf16(av[m], bv[n], acc[m][n], 0, 0, 0);
    }
    __syncthreads();   // drains prefetch vmcnt; orders buf reuse
    cur ^= 1;
  }

#pragma unroll
  for (int m = 0; m < 4; ++m) {
#pragma unroll
    for (int n = 0; n < 4; ++n) {
      const int gr0 = bm0 + wr * 64 + m * 16 + l4 * 4;
      const int gc  = bn0 + wc * 64 + n * 16 + l15;
#pragma unroll
      for (int j = 0; j < 4; ++j)
        C[(size_t)(gr0 + j) * 2048 + gc] = acc[m][n][j];
    }
  }
}

// ---------------- K2: z -> out; C1 rewritten in place to [mu_biased | mu^2+exp(ls)]; lss
__global__ __launch_bounds__(256) void k2_build(float* __restrict__ C1,
                                                const float* __restrict__ bmu,
                                                const float* __restrict__ bls,
                                                const float* __restrict__ eps,
                                                float* __restrict__ z_out,
                                                float* __restrict__ ls_sum) {
  const int b = blockIdx.x;
  const int t = threadIdx.x;
  float lsacc = 0.f;
  const size_t base2 = (size_t)b * 2048;
  const size_t base1 = (size_t)b * 1024;
#pragma unroll
  for (int i = 0; i < 4; ++i) {
    const int h = t + i * 256;
    const float mu = C1[base2 + h] + bmu[h];
    const float ls = C1[base2 + 1024 + h] + bls[h];
    const float e = eps[base1 + h];
    const float sh = expf(0.5f * ls);           // exp(ls/2)
    const float z = fmaf(sh, e, mu);
    z_out[base1 + h] = z;
    lsacc += ls;
    C1[base2 + h] = mu;                         // biased mu
    C1[base2 + 1024 + h] = fmaf(mu, mu, sh * sh);  // q = mu^2 + exp(ls)
  }
#pragma unroll
  for (int off = 32; off; off >>= 1) lsacc += __shfl_down(lsacc, off);
  __shared__ float r4[4];
  if ((t & 63) == 0) r4[t >> 6] = lsacc;
  __syncthreads();
  if (t == 0) ls_sum[b] = r4[0] + r4[1] + r4[2] + r4[3];
}

// ---------------- GEMM2: C2[8192,512] partial sums, split-K + 2 variants, 2-phase dbuf
// blockIdx.z: bit0 = variant, bit1 = K-half. A reg-staged (f32 -> split bf16), B gload_lds.
__global__ __launch_bounds__(256, 2) void gemm2_fly(const float* __restrict__ C1,
                                                    const float* __restrict__ zbuf,
                                                    const __bf16* __restrict__ W2,
                                                    float* __restrict__ Cpart) {
  const int zv = blockIdx.z & 1;
  const int ks = blockIdx.z >> 1;
  float* Cc = Cpart + ((size_t)(zv * 2 + ks)) * BB * KK;   // [m_s0][m_s1][a_s0][a_s1]

  __shared__ __align__(16) __bf16 ldsA[2][128 * 64];
  __shared__ __align__(16) __bf16 ldsB[2][128 * 64];

  const int t = threadIdx.x;
  const int wv = t >> 6, lane = t & 63;
  const int l15 = lane & 15, l4 = lane >> 4;
  const int wr = wv >> 1, wc = wv & 1;
  const int bm0 = blockIdx.x * 128;
  const int bn0 = blockIdx.y * 128;

  f32x4 acc[4][4] = {};

  auto stageB = [&](int k0, int b) {
#pragma unroll
    for (int i = 0; i < 4; ++i) {
      const int obase = i * 4096 + wv * 1024;
      const int o = obase + lane * 16;
      const int row = o >> 7;
      const int cb = o & 127;
      const int cbs = cb ^ ((row & 7) << 4);
      GLOAD_LDS16(W2 + (size_t)(bn0 + row) * 6144 + k0 + (cbs >> 1), (char*)ldsB[b] + obase);
    }
  };
  auto ldA_issue = [&](int k0, float4 fa[4][2]) {
    const int kin = k0 & 2047;
    const bool quad = kin < 1024;
    const int hcol = quad ? kin : (kin - 1024);
#pragma unroll
    for (int v = 0; v < 4; ++v) {
      const int id = v * 256 + t;
      const int row = id >> 3;
      const int c8 = id & 7;
      const size_t gr = (size_t)(bm0 + row);
      const int jc = hcol + c8 * 8;
      const float* src = (zv == 0) ? (zbuf + gr * 1024 + jc)
                                   : (C1 + gr * 2048 + (quad ? 1024 : 0) + jc);
      fa[v][0] = *(const float4*)(src);
      fa[v][1] = *(const float4*)(src + 4);
    }
  };
  auto ldA_commit = [&](int k0, const float4 fa[4][2], int b) {
    const int chunk = k0 >> 11;
    const int kin = k0 & 2047;
    const bool quad = kin < 1024;
#pragma unroll
    for (int v = 0; v < 4; ++v) {
      const int id = v * 256 + t;
      const int row = id >> 3;
      const int c8 = id & 7;
      float vals[8] = {fa[v][0].x, fa[v][0].y, fa[v][0].z, fa[v][0].w,
                       fa[v][1].x, fa[v][1].y, fa[v][1].z, fa[v][1].w};
      if (zv == 0 && quad) {
#pragma unroll
        for (int j = 0; j < 8; ++j) vals[j] = vals[j] * vals[j];
      }
      bf16x8 w;
      if (chunk < 2) {
#pragma unroll
        for (int j = 0; j < 8; ++j) w[j] = (__bf16)vals[j];
      } else {
#pragma unroll
        for (int j = 0; j < 8; ++j) {
          const __bf16 h = (__bf16)vals[j];
          w[j] = (__bf16)(vals[j] - (float)h);
        }
      }
      const int cb = c8 * 16;
      *(bf16x8*)((char*)ldsA[b] + row * 128 + (cb ^ ((row & 7) << 4))) = w;
    }
  };

  const int kbeg = ks * 3072;
  // prologue: stage tile 0 into buf 0
  {
    float4 fa[4][2];
    ldA_issue(kbeg, fa);
    stageB(kbeg, 0);
    ldA_commit(kbeg, fa, 0);
  }
  __syncthreads();
  int cur = 0;

  for (int tt = 0; tt < 48; ++tt) {
    const int k0n = kbeg + (tt + 1) * 64;
    float4 fa[4][2];
    const bool pf = (tt < 47);
    if (pf) {
      ldA_issue(k0n, fa);     // f32 loads in flight during MFMA
      stageB(k0n, cur ^ 1);   // B gload_lds in flight during MFMA
    }

#pragma unroll
    for (int kkk = 0; kkk < 2; ++kkk) {
      bf16x8 av[4], bv[4];
#pragma unroll
      for (int m = 0; m < 4; ++m) {
        const int row = wr * 64 + m * 16 + l15;
        const int cb = kkk * 64 + l4 * 16;
        av[m] = *(const bf16x8*)((const char*)ldsA[cur] + row * 128 + (cb ^ ((row & 7) << 4)));
      }
#pragma unroll
      for (int n = 0; n < 4; ++n) {
        const int row = wc * 64 + n * 16 + l15;
        const int cb = kkk * 64 + l4 * 16;
        bv[n] = *(const bf16x8*)((const char*)ldsB[cur] + row * 128 + (cb ^ ((row & 7) << 4)));
      }
#pragma unroll
      for (int m = 0; m < 4; ++m)
#pragma unroll
        for (int n = 0; n < 4; ++n)
          acc[m][n] = __builtin_amdgcn_mfma_f32_16x16x32_bf16(av[m], bv[n], acc[m][n], 0, 0, 0);
    }

    if (pf) ldA_commit(k0n, fa, cur ^ 1);   // convert + swizzled ds_write after MFMA
    __syncthreads();
    cur ^= 1;
  }

#pragma unroll
  for (int m = 0; m < 4; ++m) {
#pragma unroll
    for (int n = 0; n < 4; ++n) {
      const int gr0 = bm0 + wr * 64 + m * 16 + l4 * 4;
      const int gc  = bn0 + wc * 64 + n * 16 + l15;
#pragma unroll
      for (int j = 0; j < 4; ++j)
        Cc[(size_t)(gr0 + j) * 512 + gc] = acc[m][n][j];
    }
  }
}

// ---------------- K4: per-row softmax/loss + att column accumulation
__global__ __launch_bounds__(256) void k4_rows(const float* __restrict__ Cpart,
                                               const float* __restrict__ c2,
                                               const float* __restrict__ logdet,
                                               const float* __restrict__ ls_sum,
                                               float* __restrict__ out_loss,
                                               float* __restrict__ acc) {
  const float* C2m0 = Cpart;
  const float* C2m1 = Cpart + (size_t)BB * KK;
  const float* C2a0 = Cpart + (size_t)2 * BB * KK;
  const float* C2a1 = Cpart + (size_t)3 * BB * KK;
  const int t = threadIdx.x;
  const int wv = t >> 6, lane = t & 63;
  __shared__ float sacc[512];
  sacc[t] = 0.f; sacc[t + 256] = 0.f;
  __syncthreads();
  float c2r[8], avr[8], attsum[8];
#pragma unroll
  for (int i = 0; i < 8; ++i) {
    const int k = lane + i * 64;
    c2r[i] = c2[k];
    avr[i] = logdet[k] + c2r[i];
    attsum[i] = 0.f;
  }
  for (int r = 0; r < 8; ++r) {
    const int b = blockIdx.x * 32 + wv * 8 + r;
    const size_t rb = (size_t)b * 512;
    float mv[8], ev[8];
    float lm = 3.4e38f;
#pragma unroll
    for (int i = 0; i < 8; ++i) {
      const size_t idx = rb + lane + i * 64;
      mv[i] = C2m0[idx] + C2m1[idx] + c2r[i];   // mahal(z)
      lm = fminf(lm, mv[i]);
    }
#pragma unroll
    for (int off = 32; off; off >>= 1) lm = fminf(lm, __shfl_xor(lm, off));
    float s = 0.f, dot = 0.f;
#pragma unroll
    for (int i = 0; i < 8; ++i) {
      const size_t idx = rb + lane + i * 64;
      const float e = expf(lm - mv[i]);
      const float avg = (avr[i] + C2a0[idx] + C2a1[idx]) * (1.f / 1024.f);
      ev[i] = e;
      s += e;
      dot = fmaf(e, avg, dot);
    }
#pragma unroll
    for (int off = 32; off; off >>= 1) {
      s   += __shfl_xor(s, off);
      dot += __shfl_xor(dot, off);
    }
    const float inv_s = 1.f / s;
    if (lane == 0)
      out_loss[b] = 0.5f * (dot * inv_s) - 0.5f * (1.f + ls_sum[b] * (1.f / 1024.f));
#pragma unroll
    for (int i = 0; i < 8; ++i) attsum[i] += ev[i] * inv_s;
  }
#pragma unroll
  for (int i = 0; i < 8; ++i) atomicAdd(&sacc[lane + i * 64], attsum[i]);
  __syncthreads();
  atomicAdd(&acc[t], sacc[t]);
  atomicAdd(&acc[t + 256], sacc[t + 256]);
}

// ---------------- K6: categorical loss scalar
__global__ __launch_bounds__(512) void k6_final(const float* __restrict__ acc,
                                                float* __restrict__ out) {
  const int t = threadIdx.x;
  const float cm = acc[t] * (1.f / 8192.f);
  float v = cm * logf(cm);
#pragma unroll
  for (int off = 32; off; off >>= 1) v += __shfl_xor(v, off);
  __shared__ float r8[8];
  if ((t & 63) == 0) r8[t >> 6] = v;
  __syncthreads();
  if (t == 0) {
    float s = 0.f;
#pragma unroll
    for (int i = 0; i < 8; ++i) s += r8[i];
    out[0] = s * (1.f / 512.f);
  }
}

extern "C" void kernel_launch(void* const* d_in, const int* in_sizes, int n_in,
                              void* d_out, int out_size, void* d_ws, size_t ws_size,
                              hipStream_t stream) {
  const float* x   = (const float*)d_in[0];
  const float* Wmu = (const float*)d_in[1];
  const float* bmu = (const float*)d_in[2];
  const float* Wls = (const float*)d_in[3];
  const float* bls = (const float*)d_in[4];
  const float* muc = (const float*)d_in[5];
  const float* lsc = (const float*)d_in[6];
  const float* eps = (const float*)d_in[7];
  float* out = (float*)d_out;

  char* p = (char*)d_ws;
  auto carve = [&](size_t bytes) {
    char* r = p;
    p += (bytes + 255) & ~(size_t)255;
    return r;
  };
  // persistent
  float*  C1  = (float*) carve((size_t)BB * 2048 * 4);          // 67.1 MB
  __bf16* W2p = (__bf16*)carve((size_t)KK * 6144 * 2);          //  6.3 MB
  float*  c2v = (float*) carve(KK * 4);
  float*  ldv = (float*) carve(KK * 4);
  float*  lss = (float*) carve(BB * 4);
  float*  acc = (float*) carve(KK * 4);
  // union region: {xh, xl, W1p} (phase 1) overlaid by Cpart[4 slices] (phase 3+)
  char* uni = carve((size_t)4 * BB * KK * 4);                   // 67.1 MB
  __bf16* xh  = (__bf16*)uni;
  __bf16* xl  = (__bf16*)(uni + (size_t)BB * HH * 2);
  __bf16* W1p = (__bf16*)(uni + (size_t)BB * HH * 4);
  float*  Cpart = (float*)uni;

  float* z_out    = out;
  float* loss_out = out + (size_t)BB * HH;
  float* cate_out = loss_out + BB;

  p1_split<<<dim3(BB * HH / 1024), 256, 0, stream>>>(x, xh, xl);
  p2_w1<<<dim3(12, 2048), 256, 0, stream>>>(Wmu, Wls, W1p);
  p3_cluster<<<dim3(KK), 256, 0, stream>>>(muc, lsc, W2p, c2v, ldv, acc);

  // GEMM1: [8192 x 3072] * [2048 x 3072]^T -> C1 (mu_z | ls_z, pre-bias)
  gemm1<<<dim3(BB / 128, 2048 / 128), 256, 0, stream>>>(xh, xl, W1p, C1);

  k2_build<<<dim3(BB), 256, 0, stream>>>(C1, bmu, bls, eps, z_out, lss);

  // GEMM2: split-K x 2 variants -> 4 partial slices
  gemm2_fly<<<dim3(BB / 128, KK / 128, 4), 256, 0, stream>>>(C1, z_out, W2p, Cpart);

  k4_rows<<<dim3(BB / 32), 256, 0, stream>>>(Cpart, c2v, ldv, lss, loss_out, acc);
  k6_final<<<dim3(1), 512, 0, stream>>>(acc, cate_out);
}

// Round 7
// 417.784 us; speedup vs baseline: 1.2530x; 1.0859x over previous
//
#include <hip/hip_runtime.h>

// Problem constants
#define BB 8192
#define HH 1024
#define KK 512

typedef __bf16 bf16x8 __attribute__((ext_vector_type(8)));
typedef __bf16 bf16x4 __attribute__((ext_vector_type(4)));
typedef float  f32x4  __attribute__((ext_vector_type(4)));

#define GLOAD_LDS16(gptr, lptr)                                                   \
  __builtin_amdgcn_global_load_lds((const __attribute__((address_space(1))) void*)(gptr), \
                                   (__attribute__((address_space(3))) void*)(lptr), 16, 0, 0)

static __device__ __forceinline__ void split_bf16(float f, __bf16& hi, __bf16& lo) {
  hi = (__bf16)f;
  lo = (__bf16)(f - (float)hi);
}

// ---------------- P1: split x into hi/lo bf16 ----------------
__global__ __launch_bounds__(256) void p1_split(const float* __restrict__ x,
                                                __bf16* __restrict__ xh,
                                                __bf16* __restrict__ xl) {
  const size_t i = ((size_t)blockIdx.x * 256 + threadIdx.x) * 4;
  const float4 v = *(const float4*)(x + i);
  float f[4] = {v.x, v.y, v.z, v.w};
  bf16x4 hv, lv;
#pragma unroll
  for (int j = 0; j < 4; ++j) {
    __bf16 h, l; split_bf16(f[j], h, l);
    hv[j] = h; lv[j] = l;
  }
  *(bf16x4*)(xh + i) = hv;
  *(bf16x4*)(xl + i) = lv;
}

// ---------------- P2: build W1' [2048, 3072] = [Whi | Wlo | Whi] of [W_mu; W_ls]
__global__ __launch_bounds__(256) void p2_w1(const float* __restrict__ Wmu,
                                             const float* __restrict__ Wls,
                                             __bf16* __restrict__ W1p) {
  const int j = blockIdx.y;                       // 0..2047 output column
  const int k = blockIdx.x * 256 + threadIdx.x;   // 0..3071 reduction index
  const int c = k >> 10, h = k & 1023;
  const float* src = (j < 1024) ? Wmu : Wls;
  const float f = src[(size_t)(j & 1023) * 1024 + h];
  __bf16 hi, lo; split_bf16(f, hi, lo);
  W1p[(size_t)j * 3072 + k] = (c == 1) ? lo : hi;
}

// ---------------- P3: cluster stats + W2' [512, 4096] = [Whi | Wlo] of [inv | -2*mu_inv]
__global__ __launch_bounds__(256) void p3_cluster(const float* __restrict__ muc,
                                                  const float* __restrict__ lsc,
                                                  __bf16* __restrict__ W2p,
                                                  float* __restrict__ c2,
                                                  float* __restrict__ logdet,
                                                  float* __restrict__ acc) {
  const int k = blockIdx.x;
  const int t = threadIdx.x;
  if (t == 0) acc[k] = 0.f;
  float c2acc = 0.f, ldacc = 0.f;
  const size_t rb = (size_t)k * 4096;
#pragma unroll
  for (int i = 0; i < 4; ++i) {
    const int h = t + i * 256;
    const float l = lsc[(size_t)k * 1024 + h];
    const float m = muc[(size_t)k * 1024 + h];
    const float inv = expf(-l);
    const float mi = m * inv;
    c2acc += m * mi;
    ldacc += l;
    __bf16 h0, l0, h1, l1;
    split_bf16(inv, h0, l0);
    split_bf16(-2.f * mi, h1, l1);
    W2p[rb + h]        = h0; W2p[rb + 1024 + h] = h1;   // hi block (cols 0..2047)
    W2p[rb + 2048 + h] = l0; W2p[rb + 3072 + h] = l1;   // lo block (cols 2048..4095)
  }
#pragma unroll
  for (int off = 32; off; off >>= 1) {
    c2acc += __shfl_down(c2acc, off);
    ldacc += __shfl_down(ldacc, off);
  }
  __shared__ float r4[8];
  if ((t & 63) == 0) { r4[(t >> 6)] = c2acc; r4[4 + (t >> 6)] = ldacc; }
  __syncthreads();
  if (t == 0) {
    c2[k]     = r4[0] + r4[1] + r4[2] + r4[3];
    logdet[k] = r4[4] + r4[5] + r4[6] + r4[7];
  }
}

// ---------------- GEMM1: C1[8192,2048] = [xh|xh|xl] (K=3072) * W1p[2048,3072]^T
// 128x128 tile, BK=64, 4 waves; 2-phase double-buffered: prefetch t+1 before compute t.
__global__ __launch_bounds__(256, 2) void gemm1(const __bf16* __restrict__ Ah,
                                                const __bf16* __restrict__ Al,
                                                const __bf16* __restrict__ W,
                                                float* __restrict__ C) {
  __shared__ __align__(16) __bf16 ldsA[2][128 * 64];
  __shared__ __align__(16) __bf16 ldsB[2][128 * 64];

  const int t = threadIdx.x;
  const int wv = t >> 6, lane = t & 63;
  const int l15 = lane & 15, l4 = lane >> 4;
  const int wr = wv >> 1, wc = wv & 1;
  const int bm0 = blockIdx.x * 128;
  const int bn0 = blockIdx.y * 128;

  f32x4 acc[4][4] = {};

  auto stage = [&](int k0, int b) {
    const int chunk = k0 >> 10;
    const int kin = k0 & 1023;
    const __bf16* Abase = (chunk == 2) ? Al : Ah;
#pragma unroll
    for (int i = 0; i < 4; ++i) {
      const int obase = i * 4096 + wv * 1024;   // wave-uniform LDS byte base
      const int o = obase + lane * 16;
      const int row = o >> 7;
      const int cb = o & 127;
      const int cbs = cb ^ ((row & 7) << 4);    // inverse-swizzled source column byte
      GLOAD_LDS16(Abase + (size_t)(bm0 + row) * 1024 + kin + (cbs >> 1), (char*)ldsA[b] + obase);
      GLOAD_LDS16(W + (size_t)(bn0 + row) * 3072 + k0 + (cbs >> 1), (char*)ldsB[b] + obase);
    }
  };

  stage(0, 0);
  __syncthreads();
  int cur = 0;

  for (int tt = 0; tt < 48; ++tt) {
    if (tt < 47) stage((tt + 1) * 64, cur ^ 1);   // prefetch next tile (in flight during MFMA)

#pragma unroll
    for (int kkk = 0; kkk < 2; ++kkk) {
      bf16x8 av[4], bv[4];
#pragma unroll
      for (int m = 0; m < 4; ++m) {
        const int row = wr * 64 + m * 16 + l15;
        const int cb = kkk * 64 + l4 * 16;
        av[m] = *(const bf16x8*)((const char*)ldsA[cur] + row * 128 + (cb ^ ((row & 7) << 4)));
      }
#pragma unroll
      for (int n = 0; n < 4; ++n) {
        const int row = wc * 64 + n * 16 + l15;
        const int cb = kkk * 64 + l4 * 16;
        bv[n] = *(const bf16x8*)((const char*)ldsB[cur] + row * 128 + (cb ^ ((row & 7) << 4)));
      }
#pragma unroll
      for (int m = 0; m < 4; ++m)
#pragma unroll
        for (int n = 0; n < 4; ++n)
          acc[m][n] = __builtin_amdgcn_mfma_f32_16x16x32_bf16(av[m], bv[n], acc[m][n], 0, 0, 0);
    }
    __syncthreads();   // drains prefetch vmcnt; orders buf reuse
    cur ^= 1;
  }

#pragma unroll
  for (int m = 0; m < 4; ++m) {
#pragma unroll
    for (int n = 0; n < 4; ++n) {
      const int gr0 = bm0 + wr * 64 + m * 16 + l4 * 4;
      const int gc  = bn0 + wc * 64 + n * 16 + l15;
#pragma unroll
      for (int j = 0; j < 4; ++j)
        C[(size_t)(gr0 + j) * 2048 + gc] = acc[m][n][j];
    }
  }
}

// ---------------- K2: z -> out; C1 rewritten in place to [mu_biased | mu^2+exp(ls)]; lss
__global__ __launch_bounds__(256) void k2_build(float* __restrict__ C1,
                                                const float* __restrict__ bmu,
                                                const float* __restrict__ bls,
                                                const float* __restrict__ eps,
                                                float* __restrict__ z_out,
                                                float* __restrict__ ls_sum) {
  const int b = blockIdx.x;
  const int t = threadIdx.x;
  float lsacc = 0.f;
  const size_t base2 = (size_t)b * 2048;
  const size_t base1 = (size_t)b * 1024;
#pragma unroll
  for (int i = 0; i < 4; ++i) {
    const int h = t + i * 256;
    const float mu = C1[base2 + h] + bmu[h];
    const float ls = C1[base2 + 1024 + h] + bls[h];
    const float e = eps[base1 + h];
    const float sh = expf(0.5f * ls);           // exp(ls/2)
    const float z = fmaf(sh, e, mu);
    z_out[base1 + h] = z;
    lsacc += ls;
    C1[base2 + h] = mu;                         // biased mu
    C1[base2 + 1024 + h] = fmaf(mu, mu, sh * sh);  // q = mu^2 + exp(ls)
  }
#pragma unroll
  for (int off = 32; off; off >>= 1) lsacc += __shfl_down(lsacc, off);
  __shared__ float r4[4];
  if ((t & 63) == 0) r4[t >> 6] = lsacc;
  __syncthreads();
  if (t == 0) ls_sum[b] = r4[0] + r4[1] + r4[2] + r4[3];
}

// ---------------- GEMM2: 4 equal jobs, each K=2048, 2-phase dbuf
// jb = blockIdx.z:
//   j0: A = hi([z^2|z]),  B = Whi   (mahal(z) main)
//   j1: A = hi([z^2|z]),  B = Wlo   (mahal(z) corr 1)
//   j2: A = lo([z^2|z]),  B = Whi   (mahal(z) corr 2)
//   j3: A = hi([q|mu]),   B = Whi   (avg, bf16-only is accurate enough: linear use)
__global__ __launch_bounds__(256, 2) void gemm2_fly(const float* __restrict__ C1,
                                                    const float* __restrict__ zbuf,
                                                    const __bf16* __restrict__ W2,
                                                    float* __restrict__ Cpart) {
  const int jb = blockIdx.z;
  float* Cc = Cpart + (size_t)jb * BB * KK;
  const int bcol = (jb == 1) ? 2048 : 0;

  __shared__ __align__(16) __bf16 ldsA[2][128 * 64];
  __shared__ __align__(16) __bf16 ldsB[2][128 * 64];

  const int t = threadIdx.x;
  const int wv = t >> 6, lane = t & 63;
  const int l15 = lane & 15, l4 = lane >> 4;
  const int wr = wv >> 1, wc = wv & 1;
  const int bm0 = blockIdx.x * 128;
  const int bn0 = blockIdx.y * 128;

  f32x4 acc[4][4] = {};

  auto stageB = [&](int k0, int b) {
#pragma unroll
    for (int i = 0; i < 4; ++i) {
      const int obase = i * 4096 + wv * 1024;
      const int o = obase + lane * 16;
      const int row = o >> 7;
      const int cb = o & 127;
      const int cbs = cb ^ ((row & 7) << 4);
      GLOAD_LDS16(W2 + (size_t)(bn0 + row) * 4096 + bcol + k0 + (cbs >> 1), (char*)ldsB[b] + obase);
    }
  };
  auto ldA_issue = [&](int k0, float4 fa[4][2]) {
    const bool quad = k0 < 1024;
    const int hcol = quad ? k0 : (k0 - 1024);
#pragma unroll
    for (int v = 0; v < 4; ++v) {
      const int id = v * 256 + t;
      const int row = id >> 3;
      const int c8 = id & 7;
      const size_t gr = (size_t)(bm0 + row);
      const int jc = hcol + c8 * 8;
      const float* src = (jb < 3) ? (zbuf + gr * 1024 + jc)
                                  : (C1 + gr * 2048 + (quad ? 1024 : 0) + jc);
      fa[v][0] = *(const float4*)(src);
      fa[v][1] = *(const float4*)(src + 4);
    }
  };
  auto ldA_commit = [&](int k0, const float4 fa[4][2], int b) {
    const bool quad = k0 < 1024;
#pragma unroll
    for (int v = 0; v < 4; ++v) {
      const int id = v * 256 + t;
      const int row = id >> 3;
      const int c8 = id & 7;
      float vals[8] = {fa[v][0].x, fa[v][0].y, fa[v][0].z, fa[v][0].w,
                       fa[v][1].x, fa[v][1].y, fa[v][1].z, fa[v][1].w};
      if (jb < 3 && quad) {
#pragma unroll
        for (int j = 0; j < 8; ++j) vals[j] = vals[j] * vals[j];
      }
      bf16x8 w;
      if (jb == 2) {   // lo(A)
#pragma unroll
        for (int j = 0; j < 8; ++j) {
          const __bf16 h = (__bf16)vals[j];
          w[j] = (__bf16)(vals[j] - (float)h);
        }
      } else {         // hi(A)
#pragma unroll
        for (int j = 0; j < 8; ++j) w[j] = (__bf16)vals[j];
      }
      const int cb = c8 * 16;
      *(bf16x8*)((char*)ldsA[b] + row * 128 + (cb ^ ((row & 7) << 4))) = w;
    }
  };

  // prologue: stage tile 0 into buf 0
  {
    float4 fa[4][2];
    ldA_issue(0, fa);
    stageB(0, 0);
    ldA_commit(0, fa, 0);
  }
  __syncthreads();
  int cur = 0;

  for (int tt = 0; tt < 32; ++tt) {
    const int k0n = (tt + 1) * 64;
    float4 fa[4][2];
    const bool pf = (tt < 31);
    if (pf) {
      ldA_issue(k0n, fa);     // f32 loads in flight during MFMA
      stageB(k0n, cur ^ 1);   // B gload_lds in flight during MFMA
    }

#pragma unroll
    for (int kkk = 0; kkk < 2; ++kkk) {
      bf16x8 av[4], bv[4];
#pragma unroll
      for (int m = 0; m < 4; ++m) {
        const int row = wr * 64 + m * 16 + l15;
        const int cb = kkk * 64 + l4 * 16;
        av[m] = *(const bf16x8*)((const char*)ldsA[cur] + row * 128 + (cb ^ ((row & 7) << 4)));
      }
#pragma unroll
      for (int n = 0; n < 4; ++n) {
        const int row = wc * 64 + n * 16 + l15;
        const int cb = kkk * 64 + l4 * 16;
        bv[n] = *(const bf16x8*)((const char*)ldsB[cur] + row * 128 + (cb ^ ((row & 7) << 4)));
      }
#pragma unroll
      for (int m = 0; m < 4; ++m)
#pragma unroll
        for (int n = 0; n < 4; ++n)
          acc[m][n] = __builtin_amdgcn_mfma_f32_16x16x32_bf16(av[m], bv[n], acc[m][n], 0, 0, 0);
    }

    if (pf) ldA_commit(k0n, fa, cur ^ 1);   // convert + swizzled ds_write after MFMA
    __syncthreads();
    cur ^= 1;
  }

#pragma unroll
  for (int m = 0; m < 4; ++m) {
#pragma unroll
    for (int n = 0; n < 4; ++n) {
      const int gr0 = bm0 + wr * 64 + m * 16 + l4 * 4;
      const int gc  = bn0 + wc * 64 + n * 16 + l15;
#pragma unroll
      for (int j = 0; j < 4; ++j)
        Cc[(size_t)(gr0 + j) * 512 + gc] = acc[m][n][j];
    }
  }
}

// ---------------- K4: per-row softmax/loss + att column accumulation
__global__ __launch_bounds__(256) void k4_rows(const float* __restrict__ Cpart,
                                               const float* __restrict__ c2,
                                               const float* __restrict__ logdet,
                                               const float* __restrict__ ls_sum,
                                               float* __restrict__ out_loss,
                                               float* __restrict__ acc) {
  const float* S0 = Cpart;                          // mahal(z) main
  const float* S1 = Cpart + (size_t)BB * KK;        // mahal(z) corr 1
  const float* S2 = Cpart + (size_t)2 * BB * KK;    // mahal(z) corr 2
  const float* S3 = Cpart + (size_t)3 * BB * KK;    // avg partial
  const int t = threadIdx.x;
  const int wv = t >> 6, lane = t & 63;
  __shared__ float sacc[512];
  sacc[t] = 0.f; sacc[t + 256] = 0.f;
  __syncthreads();
  float c2r[8], avr[8], attsum[8];
#pragma unroll
  for (int i = 0; i < 8; ++i) {
    const int k = lane + i * 64;
    c2r[i] = c2[k];
    avr[i] = logdet[k] + c2r[i];
    attsum[i] = 0.f;
  }
  for (int r = 0; r < 8; ++r) {
    const int b = blockIdx.x * 32 + wv * 8 + r;
    const size_t rb = (size_t)b * 512;
    float mv[8], ev[8];
    float lm = 3.4e38f;
#pragma unroll
    for (int i = 0; i < 8; ++i) {
      const size_t idx = rb + lane + i * 64;
      mv[i] = S0[idx] + S1[idx] + S2[idx] + c2r[i];   // mahal(z)
      lm = fminf(lm, mv[i]);
    }
#pragma unroll
    for (int off = 32; off; off >>= 1) lm = fminf(lm, __shfl_xor(lm, off));
    float s = 0.f, dot = 0.f;
#pragma unroll
    for (int i = 0; i < 8; ++i) {
      const size_t idx = rb + lane + i * 64;
      const float e = expf(lm - mv[i]);
      const float avg = (avr[i] + S3[idx]) * (1.f / 1024.f);
      ev[i] = e;
      s += e;
      dot = fmaf(e, avg, dot);
    }
#pragma unroll
    for (int off = 32; off; off >>= 1) {
      s   += __shfl_xor(s, off);
      dot += __shfl_xor(dot, off);
    }
    const float inv_s = 1.f / s;
    if (lane == 0)
      out_loss[b] = 0.5f * (dot * inv_s) - 0.5f * (1.f + ls_sum[b] * (1.f / 1024.f));
#pragma unroll
    for (int i = 0; i < 8; ++i) attsum[i] += ev[i] * inv_s;
  }
#pragma unroll
  for (int i = 0; i < 8; ++i) atomicAdd(&sacc[lane + i * 64], attsum[i]);
  __syncthreads();
  atomicAdd(&acc[t], sacc[t]);
  atomicAdd(&acc[t + 256], sacc[t + 256]);
}

// ---------------- K6: categorical loss scalar
__global__ __launch_bounds__(512) void k6_final(const float* __restrict__ acc,
                                                float* __restrict__ out) {
  const int t = threadIdx.x;
  const float cm = acc[t] * (1.f / 8192.f);
  float v = cm * logf(cm);
#pragma unroll
  for (int off = 32; off; off >>= 1) v += __shfl_xor(v, off);
  __shared__ float r8[8];
  if ((t & 63) == 0) r8[t >> 6] = v;
  __syncthreads();
  if (t == 0) {
    float s = 0.f;
#pragma unroll
    for (int i = 0; i < 8; ++i) s += r8[i];
    out[0] = s * (1.f / 512.f);
  }
}

extern "C" void kernel_launch(void* const* d_in, const int* in_sizes, int n_in,
                              void* d_out, int out_size, void* d_ws, size_t ws_size,
                              hipStream_t stream) {
  const float* x   = (const float*)d_in[0];
  const float* Wmu = (const float*)d_in[1];
  const float* bmu = (const float*)d_in[2];
  const float* Wls = (const float*)d_in[3];
  const float* bls = (const float*)d_in[4];
  const float* muc = (const float*)d_in[5];
  const float* lsc = (const float*)d_in[6];
  const float* eps = (const float*)d_in[7];
  float* out = (float*)d_out;

  char* p = (char*)d_ws;
  auto carve = [&](size_t bytes) {
    char* r = p;
    p += (bytes + 255) & ~(size_t)255;
    return r;
  };
  // persistent
  float*  C1  = (float*) carve((size_t)BB * 2048 * 4);          // 67.1 MB
  __bf16* W2p = (__bf16*)carve((size_t)KK * 4096 * 2);          //  4.2 MB
  float*  c2v = (float*) carve(KK * 4);
  float*  ldv = (float*) carve(KK * 4);
  float*  lss = (float*) carve(BB * 4);
  float*  acc = (float*) carve(KK * 4);
  // union region: {xh, xl, W1p} (phase 1) overlaid by Cpart[4 slices] (phase 3+)
  char* uni = carve((size_t)4 * BB * KK * 4);                   // 67.1 MB
  __bf16* xh  = (__bf16*)uni;
  __bf16* xl  = (__bf16*)(uni + (size_t)BB * HH * 2);
  __bf16* W1p = (__bf16*)(uni + (size_t)BB * HH * 4);
  float*  Cpart = (float*)uni;

  float* z_out    = out;
  float* loss_out = out + (size_t)BB * HH;
  float* cate_out = loss_out + BB;

  p1_split<<<dim3(BB * HH / 1024), 256, 0, stream>>>(x, xh, xl);
  p2_w1<<<dim3(12, 2048), 256, 0, stream>>>(Wmu, Wls, W1p);
  p3_cluster<<<dim3(KK), 256, 0, stream>>>(muc, lsc, W2p, c2v, ldv, acc);

  // GEMM1: [8192 x 3072] * [2048 x 3072]^T -> C1 (mu_z | ls_z, pre-bias)
  gemm1<<<dim3(BB / 128, 2048 / 128), 256, 0, stream>>>(xh, xl, W1p, C1);

  k2_build<<<dim3(BB), 256, 0, stream>>>(C1, bmu, bls, eps, z_out, lss);

  // GEMM2: 4 equal K=2048 jobs -> 4 partial slices
  gemm2_fly<<<dim3(BB / 128, KK / 128, 4), 256, 0, stream>>>(C1, z_out, W2p, Cpart);

  k4_rows<<<dim3(BB / 32), 256, 0, stream>>>(Cpart, c2v, ldv, lss, loss_out, acc);
  k6_final<<<dim3(1), 512, 0, stream>>>(acc, cate_out);
}

// Round 9
// 396.686 us; speedup vs baseline: 1.3196x; 1.0532x over previous
//
#include <hip/hip_runtime.h>

// Problem constants
#define BB 8192
#define HH 1024
#define KK 512

typedef __bf16 bf16x8 __attribute__((ext_vector_type(8)));
typedef __bf16 bf16x4 __attribute__((ext_vector_type(4)));
typedef float  f32x4  __attribute__((ext_vector_type(4)));

#define GLOAD_LDS16(gptr, lptr)                                                   \
  __builtin_amdgcn_global_load_lds((const __attribute__((address_space(1))) void*)(gptr), \
                                   (__attribute__((address_space(3))) void*)(lptr), 16, 0, 0)

static __device__ __forceinline__ void split_bf16(float f, __bf16& hi, __bf16& lo) {
  hi = (__bf16)f;
  lo = (__bf16)(f - (float)hi);
}

// ---------------- P1: split x into hi/lo bf16 ----------------
__global__ __launch_bounds__(256) void p1_split(const float* __restrict__ x,
                                                __bf16* __restrict__ xh,
                                                __bf16* __restrict__ xl) {
  const size_t i = ((size_t)blockIdx.x * 256 + threadIdx.x) * 4;
  const float4 v = *(const float4*)(x + i);
  float f[4] = {v.x, v.y, v.z, v.w};
  bf16x4 hv, lv;
#pragma unroll
  for (int j = 0; j < 4; ++j) {
    __bf16 h, l; split_bf16(f[j], h, l);
    hv[j] = h; lv[j] = l;
  }
  *(bf16x4*)(xh + i) = hv;
  *(bf16x4*)(xl + i) = lv;
}

// ---------------- P2: W1' [2048, 3072] = [Whi | Wlo | Whi], rows FRAG-INTERLEAVED:
// W1p row j: g=j>>7 (128-row tile), o=j&127, n=o>>4 (frag), o16=o&15.
// n even -> W_mu, n odd -> W_ls; source col c = g*64 + (n>>1)*16 + o16.
// So gemm1 tile g covers h-cols [g*64, g*64+64), each with mu (even frag) and ls (odd frag).
__global__ __launch_bounds__(256) void p2_w1(const float* __restrict__ Wmu,
                                             const float* __restrict__ Wls,
                                             __bf16* __restrict__ W1p) {
  const int j = blockIdx.y;                       // 0..2047 W1p row
  const int k = blockIdx.x * 256 + threadIdx.x;   // 0..3071 reduction index
  const int g = j >> 7, o = j & 127;
  const int n = o >> 4, o16 = o & 15;
  const int c = g * 64 + (n >> 1) * 16 + o16;
  const float* src = (n & 1) ? Wls : Wmu;
  const int ch = k >> 10, h = k & 1023;
  const float f = src[(size_t)c * 1024 + h];
  __bf16 hi, lo; split_bf16(f, hi, lo);
  W1p[(size_t)j * 3072 + k] = (ch == 1) ? lo : hi;
}

// ---------------- P3: cluster stats + W2' [512, 4096] = [Whi | Wlo] of [inv | -2*mu_inv]
__global__ __launch_bounds__(256) void p3_cluster(const float* __restrict__ muc,
                                                  const float* __restrict__ lsc,
                                                  __bf16* __restrict__ W2p,
                                                  float* __restrict__ c2,
                                                  float* __restrict__ logdet,
                                                  float* __restrict__ acc) {
  const int k = blockIdx.x;
  const int t = threadIdx.x;
  if (t == 0) acc[k] = 0.f;
  float c2acc = 0.f, ldacc = 0.f;
  const size_t rb = (size_t)k * 4096;
#pragma unroll
  for (int i = 0; i < 4; ++i) {
    const int h = t + i * 256;
    const float l = lsc[(size_t)k * 1024 + h];
    const float m = muc[(size_t)k * 1024 + h];
    const float inv = expf(-l);
    const float mi = m * inv;
    c2acc += m * mi;
    ldacc += l;
    __bf16 h0, l0, h1, l1;
    split_bf16(inv, h0, l0);
    split_bf16(-2.f * mi, h1, l1);
    W2p[rb + h]        = h0; W2p[rb + 1024 + h] = h1;   // hi block (cols 0..2047)
    W2p[rb + 2048 + h] = l0; W2p[rb + 3072 + h] = l1;   // lo block (cols 2048..4095)
  }
#pragma unroll
  for (int off = 32; off; off >>= 1) {
    c2acc += __shfl_down(c2acc, off);
    ldacc += __shfl_down(ldacc, off);
  }
  __shared__ float r4[8];
  if ((t & 63) == 0) { r4[(t >> 6)] = c2acc; r4[4 + (t >> 6)] = ldacc; }
  __syncthreads();
  if (t == 0) {
    c2[k]     = r4[0] + r4[1] + r4[2] + r4[3];
    logdet[k] = r4[4] + r4[5] + r4[6] + r4[7];
  }
}

// ---------------- GEMM1Z: fused GEMM + reparam epilogue
// C = [xh|xh|xl] (K=3072) * W1p^T with frag-interleaved mu/ls columns.
// Epilogue per lane: mu=acc[m][2p]+b_mu, ls=acc[m][2p+1]+b_ls (same row,h) ->
// z=mu+exp(ls/2)*eps -> writes z (f32), A_z=bf16[z^2|z], A_q=bf16[mu^2+e^ls|mu], lss atomics.
__global__ __launch_bounds__(256, 2) void gemm1z(const __bf16* __restrict__ Ah,
                                                 const __bf16* __restrict__ Al,
                                                 const __bf16* __restrict__ W,
                                                 const float* __restrict__ bmu,
                                                 const float* __restrict__ bls,
                                                 const float* __restrict__ eps,
                                                 float* __restrict__ z_out,
                                                 __bf16* __restrict__ Az,
                                                 __bf16* __restrict__ Aq,
                                                 float* __restrict__ lss) {
  __shared__ __align__(16) __bf16 ldsA[2][128 * 64];
  __shared__ __align__(16) __bf16 ldsB[2][128 * 64];

  const int t = threadIdx.x;
  const int wv = t >> 6, lane = t & 63;
  const int l15 = lane & 15, l4 = lane >> 4;
  const int wr = wv >> 1, wc = wv & 1;
  const int bm0 = blockIdx.x * 128;
  const int bn0 = blockIdx.y * 128;   // W1p row tile; h-cols = blockIdx.y*64 ..+64
  const int g = blockIdx.y;

  f32x4 acc[4][4] = {};

  auto stage = [&](int k0, int b) {
    const int chunk = k0 >> 10;
    const int kin = k0 & 1023;
    const __bf16* Abase = (chunk == 2) ? Al : Ah;
#pragma unroll
    for (int i = 0; i < 4; ++i) {
      const int obase = i * 4096 + wv * 1024;   // wave-uniform LDS byte base
      const int o = obase + lane * 16;
      const int row = o >> 7;
      const int cb = o & 127;
      const int cbs = cb ^ ((row & 7) << 4);    // inverse-swizzled source column byte
      GLOAD_LDS16(Abase + (size_t)(bm0 + row) * 1024 + kin + (cbs >> 1), (char*)ldsA[b] + obase);
      GLOAD_LDS16(W + (size_t)(bn0 + row) * 3072 + k0 + (cbs >> 1), (char*)ldsB[b] + obase);
    }
  };

  stage(0, 0);
  __syncthreads();
  int cur = 0;

  for (int tt = 0; tt < 48; ++tt) {
    if (tt < 47) stage((tt + 1) * 64, cur ^ 1);   // prefetch next tile

#pragma unroll
    for (int kkk = 0; kkk < 2; ++kkk) {
      bf16x8 av[4], bv[4];
#pragma unroll
      for (int m = 0; m < 4; ++m) {
        const int row = wr * 64 + m * 16 + l15;
        const int cb = kkk * 64 + l4 * 16;
        av[m] = *(const bf16x8*)((const char*)ldsA[cur] + row * 128 + (cb ^ ((row & 7) << 4)));
      }
#pragma unroll
      for (int n = 0; n < 4; ++n) {
        const int row = wc * 64 + n * 16 + l15;
        const int cb = kkk * 64 + l4 * 16;
        bv[n] = *(const bf16x8*)((const char*)ldsB[cur] + row * 128 + (cb ^ ((row & 7) << 4)));
      }
#pragma unroll
      for (int m = 0; m < 4; ++m)
#pragma unroll
        for (int n = 0; n < 4; ++n)
          acc[m][n] = __builtin_amdgcn_mfma_f32_16x16x32_bf16(av[m], bv[n], acc[m][n], 0, 0, 0);
    }
    __syncthreads();
    cur ^= 1;
  }

  // ---- fused epilogue ----
  float lsum[4][4];   // [m][j] partial sum of ls over this wave's cols
#pragma unroll
  for (int m = 0; m < 4; ++m)
#pragma unroll
    for (int j = 0; j < 4; ++j) lsum[m][j] = 0.f;

#pragma unroll
  for (int pr = 0; pr < 2; ++pr) {
    const int h = g * 64 + (wc * 2 + pr) * 16 + l15;
    const float bm_v = bmu[h];
    const float bl_v = bls[h];
#pragma unroll
    for (int m = 0; m < 4; ++m) {
#pragma unroll
      for (int j = 0; j < 4; ++j) {
        const int row = bm0 + wr * 64 + m * 16 + l4 * 4 + j;
        const float mu = acc[m][2 * pr][j] + bm_v;
        const float ls = acc[m][2 * pr + 1][j] + bl_v;
        const float e = eps[(size_t)row * 1024 + h];
        const float sh = expf(0.5f * ls);
        const float z = fmaf(sh, e, mu);
        z_out[(size_t)row * 1024 + h] = z;
        Az[(size_t)row * 2048 + h]        = (__bf16)(z * z);
        Az[(size_t)row * 2048 + 1024 + h] = (__bf16)z;
        Aq[(size_t)row * 2048 + h]        = (__bf16)fmaf(mu, mu, sh * sh);
        Aq[(size_t)row * 2048 + 1024 + h] = (__bf16)mu;
        lsum[m][j] += ls;
      }
    }
  }
#pragma unroll
  for (int m = 0; m < 4; ++m) {
#pragma unroll
    for (int j = 0; j < 4; ++j) {
      float v = lsum[m][j];
      v += __shfl_xor(v, 1); v += __shfl_xor(v, 2);
      v += __shfl_xor(v, 4); v += __shfl_xor(v, 8);
      if (l15 == 0)
        atomicAdd(&lss[bm0 + wr * 64 + m * 16 + l4 * 4 + j], v);
    }
  }
}

// ---------------- GEMM2: 4 equal jobs, each K=2048, 2-phase dbuf
// j0: A=Az gload,  B=Whi   (mahal(z) main)
// j1: A=Az gload,  B=Wlo   (mahal(z) corr 1)
// j2: A=lo([z^2|z]) reg-staged from z, B=Whi (mahal(z) corr 2)
// j3: A=Aq gload,  B=Whi   (avg)
__global__ __launch_bounds__(256, 2) void gemm2_fly(const __bf16* __restrict__ Az,
                                                    const __bf16* __restrict__ Aq,
                                                    const float* __restrict__ zbuf,
                                                    const __bf16* __restrict__ W2,
                                                    float* __restrict__ Cpart) {
  const int jb = blockIdx.z;
  float* Cc = Cpart + (size_t)jb * BB * KK;
  const int bcol = (jb == 1) ? 2048 : 0;
  const __bf16* Asrc = (jb == 3) ? Aq : Az;

  __shared__ __align__(16) __bf16 ldsA[2][128 * 64];
  __shared__ __align__(16) __bf16 ldsB[2][128 * 64];

  const int t = threadIdx.x;
  const int wv = t >> 6, lane = t & 63;
  const int l15 = lane & 15, l4 = lane >> 4;
  const int wr = wv >> 1, wc = wv & 1;
  const int bm0 = blockIdx.x * 128;
  const int bn0 = blockIdx.y * 128;

  f32x4 acc[4][4] = {};

  auto stageB = [&](int k0, int b) {
#pragma unroll
    for (int i = 0; i < 4; ++i) {
      const int obase = i * 4096 + wv * 1024;
      const int o = obase + lane * 16;
      const int row = o >> 7;
      const int cb = o & 127;
      const int cbs = cb ^ ((row & 7) << 4);
      GLOAD_LDS16(W2 + (size_t)(bn0 + row) * 4096 + bcol + k0 + (cbs >> 1), (char*)ldsB[b] + obase);
    }
  };
  auto stageA_g = [&](int k0, int b) {
#pragma unroll
    for (int i = 0; i < 4; ++i) {
      const int obase = i * 4096 + wv * 1024;
      const int o = obase + lane * 16;
      const int row = o >> 7;
      const int cb = o & 127;
      const int cbs = cb ^ ((row & 7) << 4);
      GLOAD_LDS16(Asrc + (size_t)(bm0 + row) * 2048 + k0 + (cbs >> 1), (char*)ldsA[b] + obase);
    }
  };
  auto ldA_issue = [&](int k0, float4 fa[4][2]) {   // jb==2 only
    const bool quad = k0 < 1024;
    const int hcol = quad ? k0 : (k0 - 1024);
#pragma unroll
    for (int v = 0; v < 4; ++v) {
      const int id = v * 256 + t;
      const int row = id >> 3;
      const int c8 = id & 7;
      const float* src = zbuf + (size_t)(bm0 + row) * 1024 + hcol + c8 * 8;
      fa[v][0] = *(const float4*)(src);
      fa[v][1] = *(const float4*)(src + 4);
    }
  };
  auto ldA_commit = [&](int k0, const float4 fa[4][2], int b) {   // jb==2 only
    const bool quad = k0 < 1024;
#pragma unroll
    for (int v = 0; v < 4; ++v) {
      const int id = v * 256 + t;
      const int row = id >> 3;
      const int c8 = id & 7;
      float vals[8] = {fa[v][0].x, fa[v][0].y, fa[v][0].z, fa[v][0].w,
                       fa[v][1].x, fa[v][1].y, fa[v][1].z, fa[v][1].w};
      if (quad) {
#pragma unroll
        for (int j = 0; j < 8; ++j) vals[j] = vals[j] * vals[j];
      }
      bf16x8 w;
#pragma unroll
      for (int j = 0; j < 8; ++j) {
        const __bf16 h = (__bf16)vals[j];
        w[j] = (__bf16)(vals[j] - (float)h);
      }
      const int cb = c8 * 16;
      *(bf16x8*)((char*)ldsA[b] + row * 128 + (cb ^ ((row & 7) << 4))) = w;
    }
  };

  // prologue: stage tile 0 into buf 0
  if (jb == 2) {
    float4 fa[4][2];
    ldA_issue(0, fa);
    stageB(0, 0);
    ldA_commit(0, fa, 0);
  } else {
    stageA_g(0, 0);
    stageB(0, 0);
  }
  __syncthreads();
  int cur = 0;

  for (int tt = 0; tt < 32; ++tt) {
    const int k0n = (tt + 1) * 64;
    const bool pf = (tt < 31);
    float4 fa[4][2];
    if (pf) {
      if (jb == 2) ldA_issue(k0n, fa);
      else         stageA_g(k0n, cur ^ 1);
      stageB(k0n, cur ^ 1);
    }

#pragma unroll
    for (int kkk = 0; kkk < 2; ++kkk) {
      bf16x8 av[4], bv[4];
#pragma unroll
      for (int m = 0; m < 4; ++m) {
        const int row = wr * 64 + m * 16 + l15;
        const int cb = kkk * 64 + l4 * 16;
        av[m] = *(const bf16x8*)((const char*)ldsA[cur] + row * 128 + (cb ^ ((row & 7) << 4)));
      }
#pragma unroll
      for (int n = 0; n < 4; ++n) {
        const int row = wc * 64 + n * 16 + l15;
        const int cb = kkk * 64 + l4 * 16;
        bv[n] = *(const bf16x8*)((const char*)ldsB[cur] + row * 128 + (cb ^ ((row & 7) << 4)));
      }
#pragma unroll
      for (int m = 0; m < 4; ++m)
#pragma unroll
        for (int n = 0; n < 4; ++n)
          acc[m][n] = __builtin_amdgcn_mfma_f32_16x16x32_bf16(av[m], bv[n], acc[m][n], 0, 0, 0);
    }

    if (pf && jb == 2) ldA_commit(k0n, fa, cur ^ 1);
    __syncthreads();
    cur ^= 1;
  }

#pragma unroll
  for (int m = 0; m < 4; ++m) {
#pragma unroll
    for (int n = 0; n < 4; ++n) {
      const int gr0 = bm0 + wr * 64 + m * 16 + l4 * 4;
      const int gc  = bn0 + wc * 64 + n * 16 + l15;
#pragma unroll
      for (int j = 0; j < 4; ++j)
        Cc[(size_t)(gr0 + j) * 512 + gc] = acc[m][n][j];
    }
  }
}

// ---------------- K4: per-row softmax/loss + att column accumulation
__global__ __launch_bounds__(256) void k4_rows(const float* __restrict__ Cpart,
                                               const float* __restrict__ c2,
                                               const float* __restrict__ logdet,
                                               const float* __restrict__ ls_sum,
                                               float* __restrict__ out_loss,
                                               float* __restrict__ acc) {
  const float* S0 = Cpart;                          // mahal(z) main
  const float* S1 = Cpart + (size_t)BB * KK;        // mahal(z) corr 1
  const float* S2 = Cpart + (size_t)2 * BB * KK;    // mahal(z) corr 2
  const float* S3 = Cpart + (size_t)3 * BB * KK;    // avg partial
  const int t = threadIdx.x;
  const int wv = t >> 6, lane = t & 63;
  __shared__ float sacc[512];
  sacc[t] = 0.f; sacc[t + 256] = 0.f;
  __syncthreads();
  float c2r[8], avr[8], attsum[8];
#pragma unroll
  for (int i = 0; i < 8; ++i) {
    const int k = lane + i * 64;
    c2r[i] = c2[k];
    avr[i] = logdet[k] + c2r[i];
    attsum[i] = 0.f;
  }
  for (int r = 0; r < 8; ++r) {
    const int b = blockIdx.x * 32 + wv * 8 + r;
    const size_t rb = (size_t)b * 512;
    float mv[8], ev[8];
    float lm = 3.4e38f;
#pragma unroll
    for (int i = 0; i < 8; ++i) {
      const size_t idx = rb + lane + i * 64;
      mv[i] = S0[idx] + S1[idx] + S2[idx] + c2r[i];   // mahal(z)
      lm = fminf(lm, mv[i]);
    }
#pragma unroll
    for (int off = 32; off; off >>= 1) lm = fminf(lm, __shfl_xor(lm, off));
    float s = 0.f, dot = 0.f;
#pragma unroll
    for (int i = 0; i < 8; ++i) {
      const size_t idx = rb + lane + i * 64;
      const float e = expf(lm - mv[i]);
      const float avg = (avr[i] + S3[idx]) * (1.f / 1024.f);
      ev[i] = e;
      s += e;
      dot = fmaf(e, avg, dot);
    }
#pragma unroll
    for (int off = 32; off; off >>= 1) {
      s   += __shfl_xor(s, off);
      dot += __shfl_xor(dot, off);
    }
    const float inv_s = 1.f / s;
    if (lane == 0)
      out_loss[b] = 0.5f * (dot * inv_s) - 0.5f * (1.f + ls_sum[b] * (1.f / 1024.f));
#pragma unroll
    for (int i = 0; i < 8; ++i) attsum[i] += ev[i] * inv_s;
  }
#pragma unroll
  for (int i = 0; i < 8; ++i) atomicAdd(&sacc[lane + i * 64], attsum[i]);
  __syncthreads();
  atomicAdd(&acc[t], sacc[t]);
  atomicAdd(&acc[t + 256], sacc[t + 256]);
}

// ---------------- K6: categorical loss scalar
__global__ __launch_bounds__(512) void k6_final(const float* __restrict__ acc,
                                                float* __restrict__ out) {
  const int t = threadIdx.x;
  const float cm = acc[t] * (1.f / 8192.f);
  float v = cm * logf(cm);
#pragma unroll
  for (int off = 32; off; off >>= 1) v += __shfl_xor(v, off);
  __shared__ float r8[8];
  if ((t & 63) == 0) r8[t >> 6] = v;
  __syncthreads();
  if (t == 0) {
    float s = 0.f;
#pragma unroll
    for (int i = 0; i < 8; ++i) s += r8[i];
    out[0] = s * (1.f / 512.f);
  }
}

extern "C" void kernel_launch(void* const* d_in, const int* in_sizes, int n_in,
                              void* d_out, int out_size, void* d_ws, size_t ws_size,
                              hipStream_t stream) {
  const float* x   = (const float*)d_in[0];
  const float* Wmu = (const float*)d_in[1];
  const float* bmu = (const float*)d_in[2];
  const float* Wls = (const float*)d_in[3];
  const float* bls = (const float*)d_in[4];
  const float* muc = (const float*)d_in[5];
  const float* lsc = (const float*)d_in[6];
  const float* eps = (const float*)d_in[7];
  float* out = (float*)d_out;

  char* p = (char*)d_ws;
  auto carve = [&](size_t bytes) {
    char* r = p;
    p += (bytes + 255) & ~(size_t)255;
    return r;
  };
  // persistent
  __bf16* Az  = (__bf16*)carve((size_t)BB * 2048 * 2);          // 33.6 MB
  __bf16* Aq  = (__bf16*)carve((size_t)BB * 2048 * 2);          // 33.6 MB
  __bf16* W2p = (__bf16*)carve((size_t)KK * 4096 * 2);          //  4.2 MB
  float*  c2v = (float*) carve(KK * 4);
  float*  ldv = (float*) carve(KK * 4);
  float*  lss = (float*) carve(BB * 4);
  float*  acc = (float*) carve(KK * 4);
  // union region: {xh, xl, W1p} (phase 1) overlaid by Cpart[4 slices] (phase 3+)
  char* uni = carve((size_t)4 * BB * KK * 4);                   // 67.1 MB
  __bf16* xh  = (__bf16*)uni;
  __bf16* xl  = (__bf16*)(uni + (size_t)BB * HH * 2);
  __bf16* W1p = (__bf16*)(uni + (size_t)BB * HH * 4);
  float*  Cpart = (float*)uni;

  float* z_out    = out;
  float* loss_out = out + (size_t)BB * HH;
  float* cate_out = loss_out + BB;

  hipMemsetAsync(lss, 0, BB * sizeof(float), stream);

  p1_split<<<dim3(BB * HH / 1024), 256, 0, stream>>>(x, xh, xl);
  p2_w1<<<dim3(12, 2048), 256, 0, stream>>>(Wmu, Wls, W1p);
  p3_cluster<<<dim3(KK), 256, 0, stream>>>(muc, lsc, W2p, c2v, ldv, acc);

  // GEMM1Z: fused GEMM + reparam epilogue -> z, Az, Aq, lss
  gemm1z<<<dim3(BB / 128, 2048 / 128), 256, 0, stream>>>(xh, xl, W1p, bmu, bls, eps,
                                                         z_out, Az, Aq, lss);

  // GEMM2: 4 K=2048 jobs -> 4 partial slices
  gemm2_fly<<<dim3(BB / 128, KK / 128, 4), 256, 0, stream>>>(Az, Aq, z_out, W2p, Cpart);

  k4_rows<<<dim3(BB / 32), 256, 0, stream>>>(Cpart, c2v, ldv, lss, loss_out, acc);
  k6_final<<<dim3(1), 512, 0, stream>>>(acc, cate_out);
}